// Round 7
// baseline (554.575 us; speedup 1.0000x reference)
//
#include <hip/hip_runtime.h>
#include <cstddef>

static constexpr float ALPHA = 0.2f;
static constexpr int H = 64;
static constexpr int NBMAX = 4096;   // combined buckets (64 nodes each)
static constexpr int BTILE = 2048;   // bfill edges per block (8/thread)

typedef __attribute__((ext_vector_type(8))) short short8;
typedef __attribute__((ext_vector_type(4))) float floatx4;

__device__ __forceinline__ float lrelu(float v) { return v >= 0.0f ? v : ALPHA * v; }

__device__ __forceinline__ float b2f(unsigned short u)
{
    union { unsigned int i; float f; } x;
    x.i = ((unsigned int)u) << 16;
    return x.f;
}

__device__ __forceinline__ unsigned short f2b(float f)
{
    union { float f; unsigned int i; } x;
    x.f = f;
    unsigned int r = x.i + 0x7fffu + ((x.i >> 16) & 1u);  // RNE
    return (unsigned short)(r >> 16);
}

// ---- MFMA GEMM: out[rows,64](bf16) = act(in[rows,K] @ W[K,64] (+bias)) (* scl[row]) ----
template <int K, bool AF32, bool BIAS, bool ACT, bool SCALE>
__global__ __launch_bounds__(256) void mfma_gemm(
    const void* __restrict__ in_v, const float* __restrict__ W,
    const float* __restrict__ bias, const float* __restrict__ scl,
    unsigned short* __restrict__ out, int rows)
{
    constexpr int S = K / 32;
    __shared__ short8 WL[4 * S * 64];

    for (int f = threadIdx.x; f < 4 * S * 64; f += 256) {
        int c = f / (S * 64);
        int rem = f % (S * 64);
        int s = rem / 64;
        int l = rem % 64;
        short8 frag;
        #pragma unroll
        for (int j = 0; j < 8; ++j) {
            int k = s * 32 + (l >> 4) * 8 + j;
            int col = c * 16 + (l & 15);
            frag[j] = (short)f2b(W[k * H + col]);
        }
        WL[f] = frag;
    }
    __syncthreads();

    const int l = threadIdx.x & 63;
    const int wv = threadIdx.x >> 6;
    const int rowBase = blockIdx.x * 64 + wv * 16;
    if (rowBase >= rows) return;
    const int arow = min(rowBase + (l & 15), rows - 1);

    floatx4 acc0 = {0.f, 0.f, 0.f, 0.f};
    floatx4 acc1 = {0.f, 0.f, 0.f, 0.f};
    floatx4 acc2 = {0.f, 0.f, 0.f, 0.f};
    floatx4 acc3 = {0.f, 0.f, 0.f, 0.f};

    #pragma unroll
    for (int s = 0; s < S; ++s) {
        short8 a;
        if (AF32) {
            const float* ap = (const float*)in_v + (size_t)arow * K + s * 32 + (l >> 4) * 8;
            float4 f0 = *(const float4*)(ap + 0);
            float4 f1 = *(const float4*)(ap + 4);
            a[0] = (short)f2b(f0.x); a[1] = (short)f2b(f0.y);
            a[2] = (short)f2b(f0.z); a[3] = (short)f2b(f0.w);
            a[4] = (short)f2b(f1.x); a[5] = (short)f2b(f1.y);
            a[6] = (short)f2b(f1.z); a[7] = (short)f2b(f1.w);
        } else {
            a = *(const short8*)((const unsigned short*)in_v + (size_t)arow * K + s * 32 + (l >> 4) * 8);
        }
        acc0 = __builtin_amdgcn_mfma_f32_16x16x32_bf16(a, WL[(0 * S + s) * 64 + l], acc0, 0, 0, 0);
        acc1 = __builtin_amdgcn_mfma_f32_16x16x32_bf16(a, WL[(1 * S + s) * 64 + l], acc1, 0, 0, 0);
        acc2 = __builtin_amdgcn_mfma_f32_16x16x32_bf16(a, WL[(2 * S + s) * 64 + l], acc2, 0, 0, 0);
        acc3 = __builtin_amdgcn_mfma_f32_16x16x32_bf16(a, WL[(3 * S + s) * 64 + l], acc3, 0, 0, 0);
    }

    #pragma unroll
    for (int j = 0; j < 4; ++j) {
        int row = rowBase + (l >> 4) * 4 + j;
        if (row >= rows) continue;
        unsigned short* orow = out + (size_t)row * H;
        float sc = SCALE ? scl[row] : 1.0f;
        float v;
        int col = l & 15;
        v = acc0[j] + (BIAS ? bias[col] : 0.f);      if (ACT) v = lrelu(v); orow[col]      = f2b(v * sc);
        v = acc1[j] + (BIAS ? bias[col + 16] : 0.f); if (ACT) v = lrelu(v); orow[col + 16] = f2b(v * sc);
        v = acc2[j] + (BIAS ? bias[col + 32] : 0.f); if (ACT) v = lrelu(v); orow[col + 32] = f2b(v * sc);
        v = acc3[j] + (BIAS ? bias[col + 48] : 0.f); if (ACT) v = lrelu(v); orow[col + 48] = f2b(v * sc);
    }
}

// ---------------- combined bucket-sort CSR build (64-node buckets, data + meta) ----------------
// virtual buckets: [0, nbD) data (dst>>6), [nbD, nbD+nbM) meta.
// packed entry = (dstLocal<<17) | src   (src < 2^17, dstLocal < 64)

__global__ __launch_bounds__(256) void zero_i(int* __restrict__ p, int n)
{
    int i = blockIdx.x * 256 + threadIdx.x;
    if (i < n) p[i] = 0;
}

__global__ __launch_bounds__(256) void bhist(const int* __restrict__ dstD, const int* __restrict__ dstM,
                                             int* __restrict__ gbh, int E, int Et, int nbD, int nbT)
{
    __shared__ int lh[NBMAX];
    for (int i = threadIdx.x; i < nbT; i += 256) lh[i] = 0;
    __syncthreads();
    for (int j = blockIdx.x * 256 + threadIdx.x; j < Et; j += 256 * gridDim.x) {
        int b = (j < E) ? (dstD[j] >> 6) : (nbD + (dstM[j - E] >> 6));
        atomicAdd(&lh[b], 1);
    }
    __syncthreads();
    for (int b = threadIdx.x; b < nbT; b += 256) {
        int v = lh[b];
        if (v) atomicAdd(&gbh[b], v);
    }
}

// single-block exclusive scan (nb <= 4096, 16 per thread)
__global__ __launch_bounds__(256) void bscan(const int* __restrict__ gbh, int* __restrict__ goff,
                                             int* __restrict__ gcur, int nb)
{
    __shared__ int sp[256];
    int t = threadIdx.x;
    int base = t * 16;
    int a[16];
    int s = 0;
    #pragma unroll
    for (int u = 0; u < 16; ++u) {
        a[u] = (base + u < nb) ? gbh[base + u] : 0;
        s += a[u];
    }
    sp[t] = s;
    __syncthreads();
    for (int o = 1; o < 256; o <<= 1) {
        int y = (t >= o) ? sp[t - o] : 0;
        __syncthreads();
        sp[t] += y;
        __syncthreads();
    }
    int e = sp[t] - s;
    #pragma unroll
    for (int u = 0; u < 16; ++u) {
        if (base + u < nb) { goff[base + u] = e; gcur[base + u] = e; }
        e += a[u];
    }
}

// direct rank-scatter over the combined edge list; edges cached in registers between passes
__global__ __launch_bounds__(256) void bfill(const int* __restrict__ srcD, const int* __restrict__ dstD,
                                             const int* __restrict__ srcM, const int* __restrict__ dstM,
                                             int* __restrict__ gcur, int* __restrict__ ebuf,
                                             int E, int Et, int nbD, int nbT)
{
    __shared__ int lh[NBMAX];
    __shared__ int lst[NBMAX];
    const int t = threadIdx.x;
    const int base = blockIdx.x * BTILE;

    for (int i = t; i < nbT; i += 256) lh[i] = 0;
    __syncthreads();

    int bb[8], pk[8];
    #pragma unroll
    for (int u = 0; u < 8; ++u) {
        int j = base + u * 256 + t;
        if (j < Et) {
            int d, sv;
            if (j < E) { d = dstD[j]; sv = srcD[j]; bb[u] = d >> 6; }
            else       { d = dstM[j - E]; sv = srcM[j - E]; bb[u] = nbD + (d >> 6); }
            pk[u] = ((d & 63) << 17) | sv;
            atomicAdd(&lh[bb[u]], 1);
        } else bb[u] = -1;
    }
    __syncthreads();

    for (int b = t; b < nbT; b += 256) {
        int k = lh[b];
        lst[b] = k ? atomicAdd(&gcur[b], k) : 0;
    }
    __syncthreads();

    #pragma unroll
    for (int u = 0; u < 8; ++u) {
        if (bb[u] >= 0) {
            int pos = atomicAdd(&lst[bb[u]], 1);
            ebuf[pos] = pk[u];
        }
    }
}

// block per bucket: counting sort by dstLocal -> ee (sorted packed), plus dis
__global__ __launch_bounds__(256) void local_csr(const int* __restrict__ ebuf, const int* __restrict__ goff,
                                                 const int* __restrict__ gbh, int* __restrict__ ee,
                                                 float* __restrict__ dis, int nbD, int N, int NM)
{
    __shared__ int lcnt[64];
    __shared__ int lrs[64];
    __shared__ int lcur[64];
    const int b = blockIdx.x;
    const int t = threadIdx.x;
    const int off = goff[b];
    const int k = gbh[b];
    const bool isData = b < nbD;

    if (t < 64) lcnt[t] = 0;
    __syncthreads();
    for (int i = t; i < k; i += 256) atomicAdd(&lcnt[ebuf[off + i] >> 17], 1);
    __syncthreads();
    if (t < 64) lrs[t] = lcnt[t];
    __syncthreads();
    for (int o = 1; o < 64; o <<= 1) {
        int y = (t < 64 && t >= o) ? lrs[t - o] : 0;
        __syncthreads();
        if (t < 64) lrs[t] += y;
        __syncthreads();
    }
    if (t < 64) lcur[t] = lrs[t] - lcnt[t];
    __syncthreads();
    for (int i = t; i < k; i += 256) {
        int v = ebuf[off + i];
        int pos = atomicAdd(&lcur[v >> 17], 1);
        ee[off + pos] = v;
    }
    if (t < 64) {
        int local = (isData ? b : b - nbD) * 64 + t;
        int lim = isData ? N : NM;
        if (local < lim) {
            int dt = lcnt[t] + (isData ? 1 : 0);
            dis[(isData ? 0 : N) + local] = dt > 0 ? rsqrtf((float)dt) : 0.0f;
        }
    }
}

// ---- block-per-bucket gather over dst-sorted edges, register run-accumulate + LDS flush ----
// h pre-scaled by dis[src]; out = lrelu(dd*(sum hs[s] (+hs[d] if SELF)) + bias)
template <bool SELF, bool FINAL>
__global__ __launch_bounds__(256) void gather_s(const unsigned short* __restrict__ h,
                                                const int* __restrict__ ee,
                                                const int* __restrict__ goff, const int* __restrict__ gbh,
                                                const float* __restrict__ dis, const float* __restrict__ bias,
                                                unsigned short* __restrict__ out,
                                                const float* __restrict__ Wc, const float* __restrict__ bc,
                                                float* __restrict__ fout, int nlim)
{
    __shared__ float acc[64 * 68];   // stride 68 breaks stride-64 bank aliasing
    const int t = threadIdx.x;
    const int slot = t >> 4;
    const int fq = t & 15;
    const int b = blockIdx.x;
    const int off = goff[b];
    const int k = gbh[b];

    for (int i = t; i < 64 * 68; i += 256) acc[i] = 0.f;
    __syncthreads();

    int i = off + (k * slot) / 16;
    const int end = off + (k * (slot + 1)) / 16;
    float ax = 0.f, ay = 0.f, az = 0.f, aw = 0.f;
    int curd = -1;
    if (i < end) {
        int v = ee[i];
        ushort4 hv = *(const ushort4*)(h + (size_t)((unsigned)(v & 0x1FFFF) * 64u + fq * 4u));
        while (true) {
            const bool more = (i + 1) < end;
            int vn = 0;
            ushort4 hn = {0, 0, 0, 0};
            if (more) {   // prefetch next edge + row before consuming current
                vn = ee[i + 1];
                hn = *(const ushort4*)(h + (size_t)((unsigned)(vn & 0x1FFFF) * 64u + fq * 4u));
            }
            int dL = v >> 17;
            if (dL != curd) {
                if (curd >= 0) {
                    atomicAdd(&acc[curd * 68 + fq * 4 + 0], ax);
                    atomicAdd(&acc[curd * 68 + fq * 4 + 1], ay);
                    atomicAdd(&acc[curd * 68 + fq * 4 + 2], az);
                    atomicAdd(&acc[curd * 68 + fq * 4 + 3], aw);
                }
                curd = dL;
                ax = ay = az = aw = 0.f;
            }
            ax += b2f(hv.x); ay += b2f(hv.y); az += b2f(hv.z); aw += b2f(hv.w);
            if (!more) break;
            v = vn; hv = hn; ++i;
        }
        if (curd >= 0) {
            atomicAdd(&acc[curd * 68 + fq * 4 + 0], ax);
            atomicAdd(&acc[curd * 68 + fq * 4 + 1], ay);
            atomicAdd(&acc[curd * 68 + fq * 4 + 2], az);
            atomicAdd(&acc[curd * 68 + fq * 4 + 3], aw);
        }
    }
    __syncthreads();

    const int dbase = b * 64;
    #pragma unroll
    for (int p = 0; p < 4; ++p) {
        int dL = p * 16 + slot;
        int node = dbase + dL;
        if (node >= nlim) continue;
        float dd = dis[node];
        float rx = acc[dL * 68 + fq * 4 + 0];
        float ry = acc[dL * 68 + fq * 4 + 1];
        float rz = acc[dL * 68 + fq * 4 + 2];
        float rw = acc[dL * 68 + fq * 4 + 3];
        if (SELF) {
            ushort4 hv = *(const ushort4*)(h + (size_t)node * H + fq * 4);
            rx += b2f(hv.x); ry += b2f(hv.y); rz += b2f(hv.z); rw += b2f(hv.w);
        }
        float4 bb = *(const float4*)(bias + fq * 4);
        rx = lrelu(rx * dd + bb.x); ry = lrelu(ry * dd + bb.y);
        rz = lrelu(rz * dd + bb.z); rw = lrelu(rw * dd + bb.w);
        if (FINAL) {
            int f = fq * 4;
            float p0 = rx * Wc[(f + 0) * 2] + ry * Wc[(f + 1) * 2] + rz * Wc[(f + 2) * 2] + rw * Wc[(f + 3) * 2];
            float p1 = rx * Wc[(f + 0) * 2 + 1] + ry * Wc[(f + 1) * 2 + 1] + rz * Wc[(f + 2) * 2 + 1] + rw * Wc[(f + 3) * 2 + 1];
            #pragma unroll
            for (int o = 8; o; o >>= 1) {
                p0 += __shfl_xor(p0, o);
                p1 += __shfl_xor(p1, o);
            }
            if (fq == 0) {
                float l0 = p0 + bc[0], l1 = p1 + bc[1];
                float m = fmaxf(l0, l1);
                float lse = m + logf(expf(l0 - m) + expf(l1 - m));
                fout[(size_t)node * 2 + 0] = l0 - lse;
                fout[(size_t)node * 2 + 1] = l1 - lse;
            }
        } else {
            ushort4 o4;
            o4.x = f2b(rx); o4.y = f2b(ry); o4.z = f2b(rz); o4.w = f2b(rw);
            *(ushort4*)(out + (size_t)node * H + fq * 4) = o4;
        }
    }
}

extern "C" void kernel_launch(void* const* d_in, const int* in_sizes, int n_in,
                              void* d_out, int out_size, void* d_ws, size_t ws_size,
                              hipStream_t stream)
{
    const float* x      = (const float*)d_in[0];
    const int*   ei     = (const int*)d_in[1];
    const float* mx     = (const float*)d_in[2];
    const int*   mei    = (const int*)d_in[3];
    const float* W_lin  = (const float*)d_in[4];
    const float* b_lin  = (const float*)d_in[5];
    const float* W_mlin = (const float*)d_in[6];
    const float* b_mlin = (const float*)d_in[7];
    const float* W0     = (const float*)d_in[8];
    const float* b0     = (const float*)d_in[9];
    const float* W1     = (const float*)d_in[10];
    const float* b1     = (const float*)d_in[11];
    const float* Wm     = (const float*)d_in[12];
    const float* bm     = (const float*)d_in[13];
    const float* Wc     = (const float*)d_in[14];
    const float* bc     = (const float*)d_in[15];

    const int F  = 128;
    const int N  = in_sizes[0] / F;
    const int E  = in_sizes[1] / 2;
    const int M  = in_sizes[2] / F;
    const int Em = in_sizes[3] / 2;
    const int NM = N + M;
    const int Et = E + Em;
    const int* src  = ei;
    const int* dstp = ei + E;
    const int* msrc = mei;
    const int* mdst = mei + Em;

    unsigned short* hb0 = (unsigned short*)d_ws;        // [NM, H] bf16
    unsigned short* hb1 = hb0 + (size_t)NM * H;         // [NM, H] bf16
    float* disV = (float*)(hb1 + (size_t)NM * H);       // [N + NM]
    int*   ebuf = (int*)(disV + (N + NM));              // [Et]
    int*   ee   = ebuf + Et;                            // [Et] sorted packed
    int*   gbh  = ee + Et;                              // [NBMAX]
    int*   goff = gbh + NBMAX;                          // [NBMAX]
    int*   gcur = goff + NBMAX;                         // [NBMAX]

    const int nbD = (N + 63) / 64;
    const int nbM = (NM + 63) / 64;
    const int nbT = nbD + nbM;

    // input projections (meta rows go straight to concat slot)
    mfma_gemm<128, true, true, true, false><<<(N + 63) / 64, 256, 0, stream>>>(x, W_lin, b_lin, nullptr, hb0, N);
    mfma_gemm<128, true, true, true, false><<<(M + 63) / 64, 256, 0, stream>>>(mx, W_mlin, b_mlin, nullptr, hb0 + (size_t)N * H, M);

    // combined CSR build (data + meta graphs in one pass)
    zero_i<<<(NBMAX + 255) / 256, 256, 0, stream>>>(gbh, NBMAX);
    bhist<<<512, 256, 0, stream>>>(dstp, mdst, gbh, E, Et, nbD, nbT);
    bscan<<<1, 256, 0, stream>>>(gbh, goff, gcur, nbT);
    bfill<<<(Et + BTILE - 1) / BTILE, 256, 0, stream>>>(src, dstp, msrc, mdst, gcur, ebuf, E, Et, nbD, nbT);
    local_csr<<<nbT, 256, 0, stream>>>(ebuf, goff, gbh, ee, disV, nbD, N, NM);

    // GCN layer 0 (GEMM output pre-scaled by dis)
    mfma_gemm<64, false, false, false, true><<<(N + 63) / 64, 256, 0, stream>>>(hb0, W0, nullptr, disV, hb1, N);
    gather_s<true, false><<<nbD, 256, 0, stream>>>(hb1, ee, goff, gbh, disV, b0, hb0, nullptr, nullptr, nullptr, N);

    // GCN layer 1
    mfma_gemm<64, false, false, false, true><<<(N + 63) / 64, 256, 0, stream>>>(hb0, W1, nullptr, disV, hb1, N);
    gather_s<true, false><<<nbD, 256, 0, stream>>>(hb1, ee, goff, gbh, disV, b1, hb0, nullptr, nullptr, nullptr, N);

    // meta fusion GEMM over z = hb0[0..NM), pre-scaled by meta dis
    mfma_gemm<64, false, false, false, true><<<(NM + 63) / 64, 256, 0, stream>>>(hb0, Wm, nullptr, disV + N, hb1, NM);

    // final gather + fused classifier + log_softmax (meta buckets start at nbD)
    gather_s<false, true><<<nbM, 256, 0, stream>>>(hb1, ee, goff + nbD, gbh + nbD, disV + N, bm, nullptr, Wc, bc, (float*)d_out, NM);
}

// Round 8
// 305.271 us; speedup vs baseline: 1.8167x; 1.8167x over previous
//
#include <hip/hip_runtime.h>
#include <cstddef>

static constexpr float ALPHA = 0.2f;
static constexpr int H = 64;
static constexpr int NBMAX = 2048;   // combined buckets (128 nodes each)
static constexpr int BTILE = 2048;   // bfill edges per block (8/thread)

typedef __attribute__((ext_vector_type(8))) short short8;
typedef __attribute__((ext_vector_type(4))) float floatx4;

__device__ __forceinline__ float lrelu(float v) { return v >= 0.0f ? v : ALPHA * v; }

__device__ __forceinline__ float b2f(unsigned short u)
{
    union { unsigned int i; float f; } x;
    x.i = ((unsigned int)u) << 16;
    return x.f;
}

__device__ __forceinline__ float asf(unsigned int u)
{
    union { unsigned int i; float f; } x;
    x.i = u;
    return x.f;
}

__device__ __forceinline__ unsigned short f2b(float f)
{
    union { float f; unsigned int i; } x;
    x.f = f;
    unsigned int r = x.i + 0x7fffu + ((x.i >> 16) & 1u);  // RNE
    return (unsigned short)(r >> 16);
}

// ---- MFMA GEMM: out[rows,64](bf16) = act(in[rows,K] @ W[K,64] (+bias)) (* scl[row]) ----
template <int K, bool AF32, bool BIAS, bool ACT, bool SCALE>
__global__ __launch_bounds__(256) void mfma_gemm(
    const void* __restrict__ in_v, const float* __restrict__ W,
    const float* __restrict__ bias, const float* __restrict__ scl,
    unsigned short* __restrict__ out, int rows)
{
    constexpr int S = K / 32;
    __shared__ short8 WL[4 * S * 64];

    for (int f = threadIdx.x; f < 4 * S * 64; f += 256) {
        int c = f / (S * 64);
        int rem = f % (S * 64);
        int s = rem / 64;
        int l = rem % 64;
        short8 frag;
        #pragma unroll
        for (int j = 0; j < 8; ++j) {
            int k = s * 32 + (l >> 4) * 8 + j;
            int col = c * 16 + (l & 15);
            frag[j] = (short)f2b(W[k * H + col]);
        }
        WL[f] = frag;
    }
    __syncthreads();

    const int l = threadIdx.x & 63;
    const int wv = threadIdx.x >> 6;
    const int rowBase = blockIdx.x * 64 + wv * 16;
    if (rowBase >= rows) return;
    const int arow = min(rowBase + (l & 15), rows - 1);

    floatx4 acc0 = {0.f, 0.f, 0.f, 0.f};
    floatx4 acc1 = {0.f, 0.f, 0.f, 0.f};
    floatx4 acc2 = {0.f, 0.f, 0.f, 0.f};
    floatx4 acc3 = {0.f, 0.f, 0.f, 0.f};

    #pragma unroll
    for (int s = 0; s < S; ++s) {
        short8 a;
        if (AF32) {
            const float* ap = (const float*)in_v + (size_t)arow * K + s * 32 + (l >> 4) * 8;
            float4 f0 = *(const float4*)(ap + 0);
            float4 f1 = *(const float4*)(ap + 4);
            a[0] = (short)f2b(f0.x); a[1] = (short)f2b(f0.y);
            a[2] = (short)f2b(f0.z); a[3] = (short)f2b(f0.w);
            a[4] = (short)f2b(f1.x); a[5] = (short)f2b(f1.y);
            a[6] = (short)f2b(f1.z); a[7] = (short)f2b(f1.w);
        } else {
            a = *(const short8*)((const unsigned short*)in_v + (size_t)arow * K + s * 32 + (l >> 4) * 8);
        }
        acc0 = __builtin_amdgcn_mfma_f32_16x16x32_bf16(a, WL[(0 * S + s) * 64 + l], acc0, 0, 0, 0);
        acc1 = __builtin_amdgcn_mfma_f32_16x16x32_bf16(a, WL[(1 * S + s) * 64 + l], acc1, 0, 0, 0);
        acc2 = __builtin_amdgcn_mfma_f32_16x16x32_bf16(a, WL[(2 * S + s) * 64 + l], acc2, 0, 0, 0);
        acc3 = __builtin_amdgcn_mfma_f32_16x16x32_bf16(a, WL[(3 * S + s) * 64 + l], acc3, 0, 0, 0);
    }

    #pragma unroll
    for (int j = 0; j < 4; ++j) {
        int row = rowBase + (l >> 4) * 4 + j;
        if (row >= rows) continue;
        unsigned short* orow = out + (size_t)row * H;
        float sc = SCALE ? scl[row] : 1.0f;
        float v;
        int col = l & 15;
        v = acc0[j] + (BIAS ? bias[col] : 0.f);      if (ACT) v = lrelu(v); orow[col]      = f2b(v * sc);
        v = acc1[j] + (BIAS ? bias[col + 16] : 0.f); if (ACT) v = lrelu(v); orow[col + 16] = f2b(v * sc);
        v = acc2[j] + (BIAS ? bias[col + 32] : 0.f); if (ACT) v = lrelu(v); orow[col + 32] = f2b(v * sc);
        v = acc3[j] + (BIAS ? bias[col + 48] : 0.f); if (ACT) v = lrelu(v); orow[col + 48] = f2b(v * sc);
    }
}

// ---------------- combined bucket-sort CSR build (data graph + meta graph in one pass) ----------------
// virtual bucket space: [0, nbD) data buckets (dst>>7), [nbD, nbD+nbM) meta buckets.
// packed entry = (dstLocal<<17) | src   (src < 2^17, dstLocal < 128)

__global__ __launch_bounds__(256) void zero_i(int* __restrict__ p, int n)
{
    int i = blockIdx.x * 256 + threadIdx.x;
    if (i < n) p[i] = 0;
}

__global__ __launch_bounds__(256) void bhist(const int* __restrict__ dstD, const int* __restrict__ dstM,
                                             int* __restrict__ gbh, int E, int Et, int nbD, int nbT)
{
    __shared__ int lh[NBMAX];
    for (int i = threadIdx.x; i < nbT; i += 256) lh[i] = 0;
    __syncthreads();
    for (int j = blockIdx.x * 256 + threadIdx.x; j < Et; j += 256 * gridDim.x) {
        int b = (j < E) ? (dstD[j] >> 7) : (nbD + (dstM[j - E] >> 7));
        atomicAdd(&lh[b], 1);
    }
    __syncthreads();
    for (int b = threadIdx.x; b < nbT; b += 256) {
        int v = lh[b];
        if (v) atomicAdd(&gbh[b], v);
    }
}

// single-block exclusive scan (nb <= 2048, 8 per thread)
__global__ __launch_bounds__(256) void bscan(const int* __restrict__ gbh, int* __restrict__ goff,
                                             int* __restrict__ gcur, int nb)
{
    __shared__ int sp[256];
    int t = threadIdx.x;
    int base = t * 8;
    int a[8];
    int s = 0;
    #pragma unroll
    for (int u = 0; u < 8; ++u) {
        a[u] = (base + u < nb) ? gbh[base + u] : 0;
        s += a[u];
    }
    sp[t] = s;
    __syncthreads();
    for (int o = 1; o < 256; o <<= 1) {
        int y = (t >= o) ? sp[t - o] : 0;
        __syncthreads();
        sp[t] += y;
        __syncthreads();
    }
    int e = sp[t] - s;
    #pragma unroll
    for (int u = 0; u < 8; ++u) {
        if (base + u < nb) { goff[base + u] = e; gcur[base + u] = e; }
        e += a[u];
    }
}

// direct rank-scatter over the combined edge list; edges cached in registers between passes
__global__ __launch_bounds__(256) void bfill(const int* __restrict__ srcD, const int* __restrict__ dstD,
                                             const int* __restrict__ srcM, const int* __restrict__ dstM,
                                             int* __restrict__ gcur, int* __restrict__ ebuf,
                                             int E, int Et, int nbD, int nbT)
{
    __shared__ int lh[NBMAX];
    __shared__ int lst[NBMAX];
    const int t = threadIdx.x;
    const int base = blockIdx.x * BTILE;

    for (int i = t; i < nbT; i += 256) lh[i] = 0;
    __syncthreads();

    int bb[8], pk[8];
    #pragma unroll
    for (int u = 0; u < 8; ++u) {
        int j = base + u * 256 + t;
        if (j < Et) {
            int d, sv;
            if (j < E) { d = dstD[j]; sv = srcD[j]; bb[u] = d >> 7; }
            else       { d = dstM[j - E]; sv = srcM[j - E]; bb[u] = nbD + (d >> 7); }
            pk[u] = ((d & 127) << 17) | sv;
            atomicAdd(&lh[bb[u]], 1);
        } else bb[u] = -1;
    }
    __syncthreads();

    for (int b = t; b < nbT; b += 256) {
        int k = lh[b];
        lst[b] = k ? atomicAdd(&gcur[b], k) : 0;
    }
    __syncthreads();

    #pragma unroll
    for (int u = 0; u < 8; ++u) {
        if (bb[u] >= 0) {
            int pos = atomicAdd(&lst[bb[u]], 1);
            ebuf[pos] = pk[u];
        }
    }
}

// block per bucket: local counting sort -> esrc (dense) + rs/cnt/dis in virtual node space
__global__ __launch_bounds__(256) void local_csr(const int* __restrict__ ebuf, const int* __restrict__ goff,
                                                 const int* __restrict__ gbh, int* __restrict__ esrc,
                                                 int* __restrict__ rs, int* __restrict__ cnt,
                                                 float* __restrict__ dis, int nbD, int N, int NM)
{
    __shared__ int lcnt[128];
    __shared__ int lrs[128];
    __shared__ int lcur[128];
    const int b = blockIdx.x;
    const int t = threadIdx.x;
    const int off = goff[b];
    const int k = gbh[b];
    const bool isData = b < nbD;

    if (t < 128) lcnt[t] = 0;
    __syncthreads();
    for (int i = t; i < k; i += 256) atomicAdd(&lcnt[ebuf[off + i] >> 17], 1);
    __syncthreads();
    if (t < 128) lrs[t] = lcnt[t];
    __syncthreads();
    for (int o = 1; o < 128; o <<= 1) {
        int y = (t < 128 && t >= o) ? lrs[t - o] : 0;
        __syncthreads();
        if (t < 128) lrs[t] += y;
        __syncthreads();
    }
    if (t < 128) lcur[t] = lrs[t] - lcnt[t];
    __syncthreads();
    for (int i = t; i < k; i += 256) {
        int v = ebuf[off + i];
        int dL = v >> 17;
        int pos = atomicAdd(&lcur[dL], 1);
        esrc[off + pos] = v & 0x1FFFF;
    }
    if (t < 128) {
        int local = isData ? b * 128 + t : (b - nbD) * 128 + t;
        int lim = isData ? N : NM;
        if (local < lim) {
            int slot = isData ? local : N + local;
            int c = lcnt[t];
            rs[slot] = off + (lrs[t] - c);
            cnt[slot] = c;
            int dt = c + (isData ? 1 : 0);
            dis[slot] = dt > 0 ? rsqrtf((float)dt) : 0.0f;
        }
    }
}

// ---- wave-per-dst gather: 8 edge slots x 8 feature lanes, ushort8 (16B) loads ----
// h pre-scaled by dis[src]; out = lrelu(dd*(sum hs[s] (+hs[d] if SELF)) + bias)
template <bool SELF, bool FINAL>
__global__ __launch_bounds__(256) void gather_w8(const unsigned short* __restrict__ h,
                                                 const int* __restrict__ esrc,
                                                 const int* __restrict__ rs, const int* __restrict__ cnt,
                                                 const float* __restrict__ dis, const float* __restrict__ bias,
                                                 unsigned short* __restrict__ out,
                                                 const float* __restrict__ Wc, const float* __restrict__ bc,
                                                 float* __restrict__ fout, int n)
{
    int d = blockIdx.x * 4 + (threadIdx.x >> 6);
    if (d >= n) return;
    const int l = threadIdx.x & 63;
    const int slot = l >> 3;   // edge slot 0..7
    const int fh = l & 7;      // feature octet: features [fh*8, fh*8+8)
    const int beg = rs[d];
    const int c = cnt[d];
    const float dd = dis[d];
    const char* hb = (const char*)h;

    float a0 = 0.f, a1 = 0.f, a2 = 0.f, a3 = 0.f, a4 = 0.f, a5 = 0.f, a6 = 0.f, a7 = 0.f;
    for (int i = slot; i < c; i += 8) {
        unsigned s = (unsigned)esrc[beg + i];
        uint4 w = *(const uint4*)(hb + (s * 128u + (unsigned)fh * 16u));
        a0 += asf(w.x << 16); a1 += asf(w.x & 0xFFFF0000u);
        a2 += asf(w.y << 16); a3 += asf(w.y & 0xFFFF0000u);
        a4 += asf(w.z << 16); a5 += asf(w.z & 0xFFFF0000u);
        a6 += asf(w.w << 16); a7 += asf(w.w & 0xFFFF0000u);
    }

    // reduce across the 8 slots (lane bits 3..5)
    #pragma unroll
    for (int o = 8; o <= 32; o <<= 1) {
        a0 += __shfl_xor(a0, o); a1 += __shfl_xor(a1, o);
        a2 += __shfl_xor(a2, o); a3 += __shfl_xor(a3, o);
        a4 += __shfl_xor(a4, o); a5 += __shfl_xor(a5, o);
        a6 += __shfl_xor(a6, o); a7 += __shfl_xor(a7, o);
    }

    if (SELF) {
        uint4 w = *(const uint4*)(hb + ((unsigned)d * 128u + (unsigned)fh * 16u));
        a0 += asf(w.x << 16); a1 += asf(w.x & 0xFFFF0000u);
        a2 += asf(w.y << 16); a3 += asf(w.y & 0xFFFF0000u);
        a4 += asf(w.z << 16); a5 += asf(w.z & 0xFFFF0000u);
        a6 += asf(w.w << 16); a7 += asf(w.w & 0xFFFF0000u);
    }

    float4 bb0 = *(const float4*)(bias + fh * 8);
    float4 bb1 = *(const float4*)(bias + fh * 8 + 4);
    float r0 = lrelu(a0 * dd + bb0.x), r1 = lrelu(a1 * dd + bb0.y);
    float r2 = lrelu(a2 * dd + bb0.z), r3 = lrelu(a3 * dd + bb0.w);
    float r4 = lrelu(a4 * dd + bb1.x), r5 = lrelu(a5 * dd + bb1.y);
    float r6 = lrelu(a6 * dd + bb1.z), r7 = lrelu(a7 * dd + bb1.w);

    if (FINAL) {
        // Wc rows (f, 2): contiguous 16 floats for this lane's 8 features
        float4 wc0 = *(const float4*)(Wc + fh * 16);
        float4 wc1 = *(const float4*)(Wc + fh * 16 + 4);
        float4 wc2 = *(const float4*)(Wc + fh * 16 + 8);
        float4 wc3 = *(const float4*)(Wc + fh * 16 + 12);
        float p0 = r0 * wc0.x + r1 * wc0.z + r2 * wc1.x + r3 * wc1.z
                 + r4 * wc2.x + r5 * wc2.z + r6 * wc3.x + r7 * wc3.z;
        float p1 = r0 * wc0.y + r1 * wc0.w + r2 * wc1.y + r3 * wc1.w
                 + r4 * wc2.y + r5 * wc2.w + r6 * wc3.y + r7 * wc3.w;
        #pragma unroll
        for (int o = 4; o; o >>= 1) {
            p0 += __shfl_xor(p0, o);
            p1 += __shfl_xor(p1, o);
        }
        if (l == 0) {
            float l0 = p0 + bc[0], l1 = p1 + bc[1];
            float m = fmaxf(l0, l1);
            float lse = m + logf(expf(l0 - m) + expf(l1 - m));
            fout[(size_t)d * 2 + 0] = l0 - lse;
            fout[(size_t)d * 2 + 1] = l1 - lse;
        }
    } else {
        if (slot == 0) {
            uint4 o4;
            o4.x = (unsigned)f2b(r0) | ((unsigned)f2b(r1) << 16);
            o4.y = (unsigned)f2b(r2) | ((unsigned)f2b(r3) << 16);
            o4.z = (unsigned)f2b(r4) | ((unsigned)f2b(r5) << 16);
            o4.w = (unsigned)f2b(r6) | ((unsigned)f2b(r7) << 16);
            *(uint4*)((char*)out + ((unsigned)d * 128u + (unsigned)fh * 16u)) = o4;
        }
    }
}

extern "C" void kernel_launch(void* const* d_in, const int* in_sizes, int n_in,
                              void* d_out, int out_size, void* d_ws, size_t ws_size,
                              hipStream_t stream)
{
    const float* x      = (const float*)d_in[0];
    const int*   ei     = (const int*)d_in[1];
    const float* mx     = (const float*)d_in[2];
    const int*   mei    = (const int*)d_in[3];
    const float* W_lin  = (const float*)d_in[4];
    const float* b_lin  = (const float*)d_in[5];
    const float* W_mlin = (const float*)d_in[6];
    const float* b_mlin = (const float*)d_in[7];
    const float* W0     = (const float*)d_in[8];
    const float* b0     = (const float*)d_in[9];
    const float* W1     = (const float*)d_in[10];
    const float* b1     = (const float*)d_in[11];
    const float* Wm     = (const float*)d_in[12];
    const float* bm     = (const float*)d_in[13];
    const float* Wc     = (const float*)d_in[14];
    const float* bc     = (const float*)d_in[15];

    const int F  = 128;
    const int N  = in_sizes[0] / F;
    const int E  = in_sizes[1] / 2;
    const int M  = in_sizes[2] / F;
    const int Em = in_sizes[3] / 2;
    const int NM = N + M;
    const int Et = E + Em;
    const int* src  = ei;
    const int* dstp = ei + E;
    const int* msrc = mei;
    const int* mdst = mei + Em;

    unsigned short* hb0 = (unsigned short*)d_ws;        // [NM, H] bf16
    unsigned short* hb1 = hb0 + (size_t)NM * H;         // [NM, H] bf16
    float* disV = (float*)(hb1 + (size_t)NM * H);       // [N + NM]
    int*   cntV = (int*)(disV + (N + NM));              // [N + NM]
    int*   rsV  = cntV + (N + NM);                      // [N + NM]
    int*   esrcA = rsV + (N + NM);                      // [Et]
    int*   ebuf  = esrcA + Et;                          // [Et]
    int*   gbh  = ebuf + Et;                            // [NBMAX]
    int*   goff = gbh + NBMAX;                          // [NBMAX]
    int*   gcur = goff + NBMAX;                         // [NBMAX]

    const int nbD = (N + 127) / 128;
    const int nbM = (NM + 127) / 128;
    const int nbT = nbD + nbM;

    // input projections (meta rows go straight to concat slot)
    mfma_gemm<128, true, true, true, false><<<(N + 63) / 64, 256, 0, stream>>>(x, W_lin, b_lin, nullptr, hb0, N);
    mfma_gemm<128, true, true, true, false><<<(M + 63) / 64, 256, 0, stream>>>(mx, W_mlin, b_mlin, nullptr, hb0 + (size_t)N * H, M);

    // combined CSR build (data + meta graphs in one pass)
    zero_i<<<(NBMAX + 255) / 256, 256, 0, stream>>>(gbh, NBMAX);
    bhist<<<256, 256, 0, stream>>>(dstp, mdst, gbh, E, Et, nbD, nbT);
    bscan<<<1, 256, 0, stream>>>(gbh, goff, gcur, nbT);
    bfill<<<(Et + BTILE - 1) / BTILE, 256, 0, stream>>>(src, dstp, msrc, mdst, gcur, ebuf, E, Et, nbD, nbT);
    local_csr<<<nbT, 256, 0, stream>>>(ebuf, goff, gbh, esrcA, rsV, cntV, disV, nbD, N, NM);

    // GCN layer 0 (GEMM output pre-scaled by dis)
    mfma_gemm<64, false, false, false, true><<<(N + 63) / 64, 256, 0, stream>>>(hb0, W0, nullptr, disV, hb1, N);
    gather_w8<true, false><<<(N + 3) / 4, 256, 0, stream>>>(hb1, esrcA, rsV, cntV, disV, b0, hb0, nullptr, nullptr, nullptr, N);

    // GCN layer 1
    mfma_gemm<64, false, false, false, true><<<(N + 63) / 64, 256, 0, stream>>>(hb0, W1, nullptr, disV, hb1, N);
    gather_w8<true, false><<<(N + 3) / 4, 256, 0, stream>>>(hb1, esrcA, rsV, cntV, disV, b1, hb0, nullptr, nullptr, nullptr, N);

    // meta fusion GEMM over z = hb0[0..NM), pre-scaled by meta dis
    mfma_gemm<64, false, false, false, true><<<(NM + 63) / 64, 256, 0, stream>>>(hb0, Wm, nullptr, disV + N, hb1, NM);

    // final gather + fused classifier + log_softmax (meta CSR lives at virtual offset N)
    gather_w8<false, true><<<(NM + 3) / 4, 256, 0, stream>>>(hb1, esrcA, rsV + N, cntV + N, disV + N, bm, nullptr, Wc, bc, (float*)d_out, NM);
}